// Round 8
// baseline (53.645 us; speedup 1.0000x reference)
//
#include <hip/hip_runtime.h>

// ConvPool r8: o-split half-blocks for occupancy. fp16 MFMA 32x32x16.
// x(32,16,128,128) f32, weight(144,64), bias(64) -> out(32,64,63,63) f32.
// r3-r7 all pinned at ~40-55us with every pipe <20% busy and occupancy ~20%
// (1.6 waves/SIMD avg): latency-bound. Fix: smaller blocks, more resident.
// Block = (batch, pooled row, o-half): W slice (9KB) + 4 x-rows (16.4KB) in
// LDS = 25.7KB; ~110 VGPR under (256,4) -> 4 resident blocks (16 waves/CU),
// grid 126x32 = 4032 uniform short blocks (~15.7/CU, 4 overlapping rounds).
// W in LDS (not 72 VGPRs) removes the r5/r7 register-pressure serialization.
// Datapath = r7-verified: A=W (m=o), B=x (n=pos); pool = in-lane fmax over
// conv rows + shfl_xor(1) over the col pair; direct register stores.

typedef _Float16 f16x8 __attribute__((ext_vector_type(8)));
typedef float f32x16 __attribute__((ext_vector_type(16)));

#define MFMA16(A, B, C) __builtin_amdgcn_mfma_f32_32x32x16_f16(A, B, C, 0, 0, 0)

// ws: W frags fp16, 18432 B. off = (t*2+ot)*1024 + lane*16, lane = hf*32+(o&31),
// elem j -> k = hf*8+j: value = f16(weight[((hf*8+j)*9 + t)*64 + o])
__global__ void convert_w(const float* __restrict__ weight, char* __restrict__ ws) {
  int tau = blockIdx.x * 256 + threadIdx.x;
  if (tau >= 1152) return;          // 9 taps x 64 o x 2 k-halves
  int t = tau >> 7, r = tau & 127, o = r >> 1, hf = r & 1;
  _Float16 h[8];
#pragma unroll
  for (int j = 0; j < 8; ++j)
    h[j] = (_Float16)weight[((hf * 8 + j) * 9 + t) * 64 + o];
  int off = (t * 2 + (o >> 5)) * 1024 + (hf * 32 + (o & 31)) * 16;
  *(f16x8*)(ws + off) = *(f16x8*)h;
}

// LDS: [0,9216) W slice for this o-half: t*1024 + lane*16
//      [9216,25600) x rows: r*4096 + hf*2048 + col*16 + ch*2 (fp16)
//      [25600,25664) pad for the col-128/129 read bleed (feeds pooled col 63,
//      which is discarded).
__global__ __launch_bounds__(256, 4)
void convpool_main(const float* __restrict__ x, const char* __restrict__ ws,
                   const float* __restrict__ bias, float* __restrict__ out) {
  __shared__ __align__(16) char lds[25664];
  const int tid = threadIdx.x;
  const int bx = blockIdx.x;         // pr*2 + oh
  const int pr = bx >> 1;            // pooled row 0..62
  const int oh = bx & 1;             // o-half: o in [oh*32, oh*32+32)
  const int b = blockIdx.y;
  const int lane = tid & 63;
  const int wv = tid >> 6;           // wave -> positions [wv*32, wv*32+32)
  const int colS = tid >> 1;         // staging col
  const int hfS = tid & 1;           // staging ch-group
  const float* xb = x + (b * 16 + hfS * 8) * 16384 + colS;

  // ---- issue ALL global loads up front (no reg pressure: ~44 regs) ----
  float pv[4][8];                    // 4 input rows x 8 channels
#pragma unroll
  for (int r = 0; r < 4; ++r)
#pragma unroll
    for (int j = 0; j < 8; ++j)
      pv[r][j] = xb[j * 16384 + (2 * pr + r) * 128];

  float4 wc[3];                      // our o-half's W slice: 576 float4 total
#pragma unroll
  for (int k = 0; k < 3; ++k) {
    int idx = tid + 256 * k;
    if (idx < 576) {
      int tap = idx >> 6, off = idx & 63;
      wc[k] = *(const float4*)(ws + (tap * 2 + oh) * 1024 + off * 16);
    }
  }

  // ---- stage: W slice (linear b128) + x rows (cvt fp16, lane-contiguous) ----
#pragma unroll
  for (int k = 0; k < 3; ++k) {
    int idx = tid + 256 * k;
    if (idx < 576) {
      int tap = idx >> 6, off = idx & 63;
      *(float4*)(lds + tap * 1024 + off * 16) = wc[k];
    }
  }
#pragma unroll
  for (int r = 0; r < 4; ++r) {
    _Float16 h[8];
#pragma unroll
    for (int j = 0; j < 8; ++j) h[j] = (_Float16)pv[r][j];
    *(f16x8*)(lds + 9216 + r * 4096 + hfS * 2048 + colS * 16) = *(f16x8*)h;
  }
  __syncthreads();  // the only barrier

  // ---- 9 taps x 2 conv rows = 18 MFMA ----
  const int xbase = 9216 + (lane >> 5) * 2048 + (wv * 32 + (lane & 31)) * 16;
  f32x16 a0, a1;    // acc for conv row 0 / 1
#pragma unroll
  for (int q = 0; q < 16; ++q) { a0[q] = 0.f; a1[q] = 0.f; }
#pragma unroll
  for (int t = 0; t < 9; ++t) {
    const int n = t / 3, m = t - 3 * n;
    f16x8 Wt = *(const f16x8*)(lds + t * 1024 + lane * 16);
    f16x8 X0 = *(const f16x8*)(lds + n * 4096 + xbase + m * 16);
    f16x8 X1 = *(const f16x8*)(lds + (n + 1) * 4096 + xbase + m * 16);
    a0 = MFMA16(Wt, X0, a0);
    a1 = MFMA16(Wt, X1, a1);
  }

  // ---- pool + bias + relu + direct store (r7-verified mapping) ----
  const int c31 = lane & 31;
  const int half = lane >> 5;
  const int pw = wv * 16 + (c31 >> 1);
  const bool doit = ((c31 & 1) == 0) && (pw < 63);
  const int obase = ((b * 64) * 63 + pr) * 63 + pw;  // + o*3969
#pragma unroll
  for (int q = 0; q < 16; ++q) {
    const int o0 = oh * 32 + (q & 3) + 8 * (q >> 2);  // o = o0 + 4*half
    float v = fmaxf(a0[q], a1[q]);                    // pool conv rows
    v = fmaxf(v, __shfl_xor(v, 1, 64));               // pool col pair
    float bv = half ? bias[o0 + 4] : bias[o0];
    v = fmaxf(v + bv, 0.0f);
    if (doit) out[obase + (o0 + 4 * half) * 3969] = v;
  }
}

extern "C" void kernel_launch(void* const* d_in, const int* in_sizes, int n_in,
                              void* d_out, int out_size, void* d_ws, size_t ws_size,
                              hipStream_t stream) {
  const float* x = (const float*)d_in[0];
  const float* wgt = (const float*)d_in[1];
  const float* bias = (const float*)d_in[2];
  float* out = (float*)d_out;
  char* ws = (char*)d_ws;  // needs 18432 B
  convert_w<<<dim3(5), 256, 0, stream>>>(wgt, ws);
  convpool_main<<<dim3(126, 32), 256, 0, stream>>>(x, ws, bias, out);
}

// Round 10
// 44.067 us; speedup vs baseline: 1.2174x; 1.2174x over previous
//
#include <hip/hip_runtime.h>

// ConvPool r9b (resubmit of r9 after infra-only UnresponsiveContainer).
// Two-pass. Pass 1 streams x fp32 [b][ch][row][col] -> xh fp16
// [b][row][col][ch] (the im2col-friendly layout) once at HBM rate; pass 2
// stages rows via global_load_lds (linear, zero-VALU) and runs the verified
// fp16 MFMA datapath with ONE barrier per block.
// x(32,16,128,128) f32, weight(144,64), bias(64) -> out(32,64,63,63) f32.
// Rationale: r2-r8 all paid a per-block scalar-gather transpose (32 loads +
// 32 cvt per thread) and barrier-drained the latency; every pipe <30% busy.
// fillBufferAligned proves 6.6 TB/s is reachable; make both passes stream.

typedef _Float16 f16x8 __attribute__((ext_vector_type(8)));
typedef float f32x16 __attribute__((ext_vector_type(16)));

#define MFMA16(A, B, C) __builtin_amdgcn_mfma_f32_32x32x16_f16(A, B, C, 0, 0, 0)
#define XH_BYTES 16777216  // 32*128*128*2 granules * 16 B = 16 MiB

#define GLOAD_LDS16(g, l)                                                    \
  __builtin_amdgcn_global_load_lds(                                          \
      (const __attribute__((address_space(1))) void*)(g),                    \
      (__attribute__((address_space(3))) void*)(l), 16, 0, 0)

// blocks [0,4096): xh granule g = (b,row,col,hf): 8 ch fp16 at xh + g*16,
//   value[j] = f16(x[b][hf*8+j][row][col]).
// blocks [4096,4101): W frags (r7/r8-verified layout):
//   ws2 + (t*2+ot)*1024 + (hf*32+(o&31))*16 + j*2 = f16(weight[((hf*8+j)*9+t)*64+o])
__global__ void convert_xw(const float* __restrict__ x,
                           const float* __restrict__ weight,
                           char* __restrict__ ws) {
  const int n = blockIdx.x;
  if (n < 4096) {
    const int g = n * 256 + threadIdx.x;
    const int hf = g & 1, col = (g >> 1) & 127, row = (g >> 8) & 127, b = g >> 15;
    _Float16 h[8];
#pragma unroll
    for (int j = 0; j < 8; ++j)
      h[j] = (_Float16)x[((b * 16 + hf * 8 + j) * 128 + row) * 128 + col];
    *(f16x8*)(ws + g * 16) = *(f16x8*)h;
  } else {
    const int tau = (n - 4096) * 256 + threadIdx.x;
    if (tau >= 1152) return;  // 9 taps x 64 o x 2 k-halves
    const int t = tau >> 7, r = tau & 127, o = r >> 1, hf = r & 1;
    _Float16 h[8];
#pragma unroll
    for (int j = 0; j < 8; ++j)
      h[j] = (_Float16)weight[((hf * 8 + j) * 9 + t) * 64 + o];
    const int off = (t * 2 + (o >> 5)) * 1024 + (hf * 32 + (o & 31)) * 16;
    *(f16x8*)(ws + XH_BYTES + off) = *(f16x8*)h;
  }
}

// LDS: 10 row slots, slot r = input row rb+r: r*4096 + col*32 + hf*16 + ch*2.
// Reads bleed to (pos+m) <= 129 -> next slot / pad: feeds only pos>=126
// (pooled col 63, discarded). Max read addr 41023 -> lds[41024].
__global__ __launch_bounds__(256, 3)
void convpool_main(const char* __restrict__ ws, const float* __restrict__ bias,
                   float* __restrict__ out) {
  __shared__ __align__(16) char lds[41024];
  const int tid = threadIdx.x;
  const int s = blockIdx.x;            // strip: pooled rows 4s..(4s+nsteps-1)
  const int b = blockIdx.y;
  const int nsteps = (s < 15) ? 4 : 3; // 63 = 15*4 + 3
  const int rb = 8 * s;                // input rows rb..rb+9 (rb..rb+7 at s=15)
  const int lane = tid & 63;
  const int ph = tid >> 6;             // wave -> positions [ph*32, ph*32+32)
  const int half = lane >> 5;          // k-half (ch 0-7 / 8-15)
  const int c31 = lane & 31;

  // ---- prologue: 10 rows -> LDS, direct (one global_load_lds each) ----
  const char* xrow = ws + (size_t)(b * 128 + rb) * 4096 + tid * 16;
#pragma unroll
  for (int r = 0; r < 10; ++r)
    if (rb + r < 128)  // wave-uniform guard (s=15 skips rows 8,9)
      GLOAD_LDS16(xrow + r * 4096, lds + r * 4096 + tid * 16);

  // ---- W frags -> registers (72 VGPR, L2-resident) ----
  const char* wsW = ws + XH_BYTES;
  f16x8 W[9][2];
#pragma unroll
  for (int t = 0; t < 9; ++t)
#pragma unroll
    for (int ot = 0; ot < 2; ++ot)
      W[t][ot] = *(const f16x8*)(wsW + (t * 2 + ot) * 1024 + lane * 16);

  __syncthreads();  // the only barrier (drains the global_load_lds queue)

  const int xoff = (ph * 32 + c31) * 32 + half * 16;
  const int pw = ph * 16 + (c31 >> 1);
  const bool doit = ((c31 & 1) == 0) && (pw < 63);

  for (int i = 0; i < nsteps; ++i) {
    f32x16 acc[2][2];  // [o-tile][conv-row]
#pragma unroll
    for (int q = 0; q < 16; ++q) {
      acc[0][0][q] = 0.f; acc[0][1][q] = 0.f;
      acc[1][0][q] = 0.f; acc[1][1][q] = 0.f;
    }
    __builtin_amdgcn_s_setprio(1);
#pragma unroll
    for (int t = 0; t < 9; ++t) {
      const int n = t / 3, m = t - 3 * n;
      const int a0 = (2 * i + n) * 4096 + xoff + m * 32;  // conv row 0
      f16x8 X0 = *(const f16x8*)(lds + a0);
      f16x8 X1 = *(const f16x8*)(lds + a0 + 4096);        // conv row 1
      acc[0][0] = MFMA16(W[t][0], X0, acc[0][0]);
      acc[1][0] = MFMA16(W[t][1], X0, acc[1][0]);
      acc[0][1] = MFMA16(W[t][0], X1, acc[0][1]);
      acc[1][1] = MFMA16(W[t][1], X1, acc[1][1]);
    }
    __builtin_amdgcn_s_setprio(0);

    // ---- pool + bias + relu + direct store (r7/r8-verified mapping) ----
    const int p = 4 * s + i;
    const int obase = ((b * 64) * 63 + p) * 63 + pw;  // + o*3969
#pragma unroll
    for (int ot = 0; ot < 2; ++ot)
#pragma unroll
      for (int q = 0; q < 16; ++q) {
        const int o0 = ot * 32 + (q & 3) + 8 * (q >> 2);  // o = o0 + 4*half
        float v = fmaxf(acc[ot][0][q], acc[ot][1][q]);    // pool conv rows
        v = fmaxf(v, __shfl_xor(v, 1, 64));               // pool col pair
        const float bv = half ? bias[o0 + 4] : bias[o0];
        v = fmaxf(v + bv, 0.0f);
        if (doit) out[obase + (o0 + 4 * half) * 3969] = v;
      }
  }
}

extern "C" void kernel_launch(void* const* d_in, const int* in_sizes, int n_in,
                              void* d_out, int out_size, void* d_ws, size_t ws_size,
                              hipStream_t stream) {
  const float* x = (const float*)d_in[0];
  const float* wgt = (const float*)d_in[1];
  const float* bias = (const float*)d_in[2];
  float* out = (float*)d_out;
  char* ws = (char*)d_ws;  // uses 16 MiB (xh) + 18 KiB (W frags)
  convert_xw<<<dim3(4101), 256, 0, stream>>>(x, wgt, ws);
  convpool_main<<<dim3(16, 32), 256, 0, stream>>>(ws, bias, out);
}

// Round 11
// 39.023 us; speedup vs baseline: 1.3747x; 1.1292x over previous
//
#include <hip/hip_runtime.h>

// ConvPool r11: two-pass; main = 2048 small staggered blocks.
// x(32,16,128,128) f32, weight(144,64), bias(64) -> out(32,64,63,63) f32.
// Theory: r4/r7/r9's ~512-block grids are fully resident -> all blocks move
// through {prologue-drain, compute, store} in lockstep, so phases sum instead
// of overlapping (every pipe <20% busy). Fix: block = (b, strip of 2 pooled
// rows, o-half): 24KB prologue, ~100 VGPR under (256,4) -> 4 resident + 8
// queued blocks/CU; queued blocks stagger the phases. o-half pairs are
// mapped 32 apart in blockIdx.x (same XCD mod 8) so the pair shares xh in L2.
// Pass 1 (unchanged, r9-verified): x -> xh fp16 [b][row][col][ch] + W frags.

typedef _Float16 f16x8 __attribute__((ext_vector_type(8)));
typedef float f32x16 __attribute__((ext_vector_type(16)));

#define MFMA16(A, B, C) __builtin_amdgcn_mfma_f32_32x32x16_f16(A, B, C, 0, 0, 0)
#define XH_BYTES 16777216  // 32*128*128*2 granules * 16 B = 16 MiB

#define GLOAD_LDS16(g, l)                                                    \
  __builtin_amdgcn_global_load_lds(                                          \
      (const __attribute__((address_space(1))) void*)(g),                    \
      (__attribute__((address_space(3))) void*)(l), 16, 0, 0)

// blocks [0,4096): xh granule g = (b,row,col,hf): 8 ch fp16 at xh + g*16,
//   value[j] = f16(x[b][hf*8+j][row][col]).
// blocks [4096,4101): W frags (r7-r9-verified layout):
//   ws + XH + (t*2+ot)*1024 + (hf*32+(o&31))*16 + j*2
//   = f16(weight[((hf*8+j)*9+t)*64 + o])
__global__ void convert_xw(const float* __restrict__ x,
                           const float* __restrict__ weight,
                           char* __restrict__ ws) {
  const int n = blockIdx.x;
  if (n < 4096) {
    const int g = n * 256 + threadIdx.x;
    const int hf = g & 1, col = (g >> 1) & 127, row = (g >> 8) & 127, b = g >> 15;
    _Float16 h[8];
#pragma unroll
    for (int j = 0; j < 8; ++j)
      h[j] = (_Float16)x[((b * 16 + hf * 8 + j) * 128 + row) * 128 + col];
    *(f16x8*)(ws + g * 16) = *(f16x8*)h;
  } else {
    const int tau = (n - 4096) * 256 + threadIdx.x;
    if (tau >= 1152) return;  // 9 taps x 64 o x 2 k-halves
    const int t = tau >> 7, r = tau & 127, o = r >> 1, hf = r & 1;
    _Float16 h[8];
#pragma unroll
    for (int j = 0; j < 8; ++j)
      h[j] = (_Float16)weight[((hf * 8 + j) * 9 + t) * 64 + o];
    const int off = (t * 2 + (o >> 5)) * 1024 + (hf * 32 + (o & 31)) * 16;
    *(f16x8*)(ws + XH_BYTES + off) = *(f16x8*)h;
  }
}

// LDS: 6 row slots, slot r = input row rb+r: r*4096 + col*32 + hf*16 + ch*2.
// Reads bleed to col <= 129 -> next slot / pad: feeds only pos>=126
// (pooled col 63, discarded by pw<63). Max read addr 24624+16 -> lds[24640].
__global__ __launch_bounds__(256, 4)
void convpool_main(const char* __restrict__ ws, const float* __restrict__ bias,
                   float* __restrict__ out) {
  __shared__ __align__(16) char lds[24640];
  const int tid = threadIdx.x;
  const int bx = blockIdx.x;           // s + 32*oh  (o-half pairs 32 apart)
  const int oh = bx >> 5;              // o-tile: o in [oh*32, oh*32+32)
  const int s = bx & 31;               // strip: pooled rows 2s, 2s+1 (s=31: one)
  const int b = blockIdx.y;
  const int nsteps = (s < 31) ? 2 : 1;
  const int rb = 4 * s;                // input rows rb..rb+5 (rb..rb+3 at s=31)
  const int lane = tid & 63;
  const int ph = tid >> 6;             // wave -> positions [ph*32, ph*32+32)
  const int half = lane >> 5;          // k-half (ch 0-7 / 8-15)
  const int c31 = lane & 31;

  // ---- prologue: 6 rows -> LDS direct (one global_load_lds each) ----
  const char* xrow = ws + (size_t)(b * 128 + rb) * 4096 + tid * 16;
#pragma unroll
  for (int r = 0; r < 6; ++r)
    if (rb + r < 128)  // wave-uniform guard (s=31 skips rows 4,5)
      GLOAD_LDS16(xrow + r * 4096, lds + r * 4096 + tid * 16);

  // ---- this o-half's W frags -> registers (36 VGPR, L2-resident) ----
  const char* wsW = ws + XH_BYTES;
  f16x8 W[9];
#pragma unroll
  for (int t = 0; t < 9; ++t)
    W[t] = *(const f16x8*)(wsW + (t * 2 + oh) * 1024 + lane * 16);

  __syncthreads();  // the only barrier (drains the global_load_lds queue)

  const int xoff = (ph * 32 + c31) * 32 + half * 16;
  const int pw = ph * 16 + (c31 >> 1);
  const bool doit = ((c31 & 1) == 0) && (pw < 63);

  for (int i = 0; i < nsteps; ++i) {
    f32x16 a0, a1;  // conv row 0 / 1 accumulators
#pragma unroll
    for (int q = 0; q < 16; ++q) { a0[q] = 0.f; a1[q] = 0.f; }
    __builtin_amdgcn_s_setprio(1);
#pragma unroll
    for (int t = 0; t < 9; ++t) {
      const int n = t / 3, m = t - 3 * n;
      const int ad = (2 * i + n) * 4096 + xoff + m * 32;  // conv row 0
      f16x8 X0 = *(const f16x8*)(lds + ad);
      f16x8 X1 = *(const f16x8*)(lds + ad + 4096);        // conv row 1
      a0 = MFMA16(W[t], X0, a0);
      a1 = MFMA16(W[t], X1, a1);
    }
    __builtin_amdgcn_s_setprio(0);

    // ---- pool + bias + relu + direct store (r7-r9-verified mapping) ----
    const int p = 2 * s + i;
    const int obase = ((b * 64) * 63 + p) * 63 + pw;  // + o*3969
#pragma unroll
    for (int q = 0; q < 16; ++q) {
      const int o0 = oh * 32 + (q & 3) + 8 * (q >> 2);  // o = o0 + 4*half
      float v = fmaxf(a0[q], a1[q]);                    // pool conv rows
      v = fmaxf(v, __shfl_xor(v, 1, 64));               // pool col pair
      const float bv = half ? bias[o0 + 4] : bias[o0];
      v = fmaxf(v + bv, 0.0f);
      if (doit) out[obase + (o0 + 4 * half) * 3969] = v;
    }
  }
}

extern "C" void kernel_launch(void* const* d_in, const int* in_sizes, int n_in,
                              void* d_out, int out_size, void* d_ws, size_t ws_size,
                              hipStream_t stream) {
  const float* x = (const float*)d_in[0];
  const float* wgt = (const float*)d_in[1];
  const float* bias = (const float*)d_in[2];
  float* out = (float*)d_out;
  char* ws = (char*)d_ws;  // uses 16 MiB (xh) + 18 KiB (W frags)
  convert_xw<<<dim3(4101), 256, 0, stream>>>(x, wgt, ws);
  convpool_main<<<dim3(64, 32), 256, 0, stream>>>(ws, bias, out);
}